// Round 2
// baseline (914.130 us; speedup 1.0000x reference)
//
#include <hip/hip_runtime.h>
#include <cstdint>
#include <cstddef>

#define BATCH 256
#define SEQ   512
#define HID   512
#define VOCAB 128

#define BT     16              // batch rows per block
#define HSTRB  528             // h-buffer row stride in BYTES (512 + 16, 16B-aligned)
#define LUTN   16384           // tanh LUT entries (16 KB LDS); idx = round(z*2048) + 8192

typedef __attribute__((ext_vector_type(4))) int   i32x4;

// tanh(z) = 1 - 2/(e^{2z}+1); saturates correctly at +/-inf
static __device__ __forceinline__ float fast_tanh(float z) {
  float e = __expf(2.f * z);
  return 1.f - 2.f * __builtin_amdgcn_rcpf(e + 1.f);
}

// ---- abs-max reduction (for quantization scales) ----
__global__ void maxred_kernel(const float* __restrict__ src, int n,
                              unsigned int* __restrict__ dst) {
  float m = 0.f;
  for (int i = blockIdx.x * blockDim.x + threadIdx.x; i < n; i += gridDim.x * blockDim.x)
    m = fmaxf(m, fabsf(src[i]));
#pragma unroll
  for (int off = 32; off; off >>= 1)
    m = fmaxf(m, __shfl_down(m, off));
  if ((threadIdx.x & 63) == 0) atomicMax(dst, __float_as_uint(m));
}

// E'[v][j] = (sum_k emb[v][k]*W_ih[k][j] + b_ih[j] + b_hh[j]) * 2048 + 8192.5
// Pre-baked tanh-LUT index transform: recurrence computes idx_f = acc*fq + E'.
__global__ __launch_bounds__(512) void eproj_kernel(const float* __restrict__ emb,
                                                    const float* __restrict__ W_ih,
                                                    const float* __restrict__ b_ih,
                                                    const float* __restrict__ b_hh,
                                                    float* __restrict__ E) {
  __shared__ float es[8][64];
  const int j = threadIdx.x;
  const int v0 = blockIdx.x * 8;
  float acc[8];
#pragma unroll
  for (int v = 0; v < 8; ++v) acc[v] = 0.f;
  for (int k0 = 0; k0 < HID; k0 += 64) {
    __syncthreads();
    es[j >> 6][j & 63] = emb[(size_t)(v0 + (j >> 6)) * HID + k0 + (j & 63)];
    __syncthreads();
#pragma unroll 8
    for (int kk = 0; kk < 64; ++kk) {
      const float w = W_ih[(size_t)(k0 + kk) * HID + j];
#pragma unroll
      for (int v = 0; v < 8; ++v) acc[v] += es[v][kk] * w;
    }
  }
  const float bias = b_ih[j] + b_hh[j];
#pragma unroll
  for (int v = 0; v < 8; ++v)
    E[(size_t)(v0 + v) * HID + j] = (acc[v] + bias) * 2048.f + 8192.5f;
}

// Pack [W_hh | W_ho] (512 x 640) into i8 MFMA B-fragments for 16x16x64.
// Fragment f = nt*8+kt8: lane l holds 16 i8 = B[k = kt8*64 + (l>>4)*16 + i][n = nt*16 + (l&15)]
__global__ void pack8_kernel(const float* __restrict__ W_hh,
                             const float* __restrict__ W_ho,
                             const float* __restrict__ sc,   // sc[0]=max|W_hh|, sc[1]=max|W_ho|
                             uint4* __restrict__ Wf8) {
  const int f = blockIdx.x;            // 0..319 (40 nt * 8 kt8)
  const int nt = f >> 3, kt8 = f & 7;
  const int lane = threadIdx.x;
  const int q = lane >> 4, nn = lane & 15;
  const int n = nt * 16 + nn;
  const float inv = 127.f / ((nt < 32) ? sc[0] : sc[1]);
  union { int8_t b[16]; uint4 u; } val;
#pragma unroll
  for (int i = 0; i < 16; ++i) {
    const int k = kt8 * 64 + q * 16 + i;
    const float w = (n < HID) ? W_hh[(size_t)k * HID + n]
                              : W_ho[(size_t)k * VOCAB + (n - HID)];
    val.b[i] = (int8_t)__float2int_rn(w * inv);
  }
  Wf8[(size_t)f * 64 + lane] = val.u;
}

// Recurrence: h_t = tanh(E[x_t] + h_{t-1} @ W_hh), all-i8 MFMA, tanh via 16K i8 LDS LUT.
// Y is FUSED: during step t's K-loop we also compute y_{t-1} = h_{t-1} @ W_ho (one extra
// MFMA per kt, W_ho strip pinned in AGPRs), epilogue after the publish barrier.
// 16 blocks x 512 threads (8 waves, 2/SIMD). Wave w owns h n-tiles w*4..w*4+3 and y cols
// w*16..w*16+15. No Hall buffer, no separate ygemm pass.
__global__ __launch_bounds__(512, 2)
void rnn_kernel(const int* __restrict__ x,
                const float* __restrict__ E,
                const uint4* __restrict__ Wf8,
                const float* __restrict__ sc,
                const float* __restrict__ b_o,
                float* __restrict__ out,
                float* __restrict__ outH) {
  __shared__ __align__(16) int8_t hbuf[BT][HSTRB];   // 8448 B
  __shared__ __align__(16) int8_t lut[LUTN];         // 16 KB: lut[i] = rnd(127*tanh((i-8192)/2048))

  const int tid = threadIdx.x;
  const int wave = tid >> 6, lane = tid & 63;
  const int q = lane >> 4, nn = lane & 15;
  const int r0 = blockIdx.x * BT;
  // idx_f = (float)acc * fq + E'  with  fq = s_w/127^2 * 2048
  const float fq = sc[0] * (2048.f / (127.f * 127.f));
  const float fy = sc[1] * (1.f / (127.f * 127.f));
  const float bo = b_o[wave * 16 + nn];

  // one-time tanh LUT fill (32 entries/thread)
  for (int i = tid; i < LUTN; i += 512) {
    const float z = ((float)i - 8192.f) * (1.f / 2048.f);
    lut[i] = (int8_t)__float2int_rn(fast_tanh(z) * 127.f);
  }

  // 5 weight strips per wave: h-tiles nt=wave*4+j (j<2 AGPR, j>=2 VGPR) + y-tile nt=32+wave (AGPR)
  i32x4 wa[2][8], wv[2][8], wy[8];
  {
    const uint4* wb = Wf8 + lane;
#pragma unroll
    for (int j = 0; j < 2; ++j)
#pragma unroll
      for (int kt = 0; kt < 8; ++kt)
        wa[j][kt] = __builtin_bit_cast(i32x4, wb[(size_t)((wave * 4 + j) * 8 + kt) * 64]);
#pragma unroll
    for (int j = 0; j < 2; ++j)
#pragma unroll
      for (int kt = 0; kt < 8; ++kt)
        wv[j][kt] = __builtin_bit_cast(i32x4, wb[(size_t)((wave * 4 + 2 + j) * 8 + kt) * 64]);
#pragma unroll
    for (int kt = 0; kt < 8; ++kt)
      wy[kt] = __builtin_bit_cast(i32x4, wb[(size_t)((32 + wave) * 8 + kt) * 64]);
  }
#pragma unroll
  for (int j = 0; j < 2; ++j)
#pragma unroll
    for (int kt = 0; kt < 8; ++kt)
      asm volatile("" : "+a"(wa[j][kt]));
#pragma unroll
  for (int j = 0; j < 2; ++j)
#pragma unroll
    for (int kt = 0; kt < 8; ++kt)
      asm volatile("" : "+v"(wv[j][kt]));
#pragma unroll
  for (int kt = 0; kt < 8; ++kt)
    asm volatile("" : "+a"(wy[kt]));

  __syncthreads();   // LUT visible to all waves

  // token prefetch for t=0
  int tokc[4];
#pragma unroll
  for (int r = 0; r < 4; ++r) tokc[r] = x[(size_t)(r0 + q * 4 + r) * SEQ + 0];

  for (int t = 0; t < SEQ; ++t) {
    int tokn[4];
    const int tn = (t + 1 < SEQ) ? t + 1 : t;
#pragma unroll
    for (int r = 0; r < 4; ++r) tokn[r] = x[(size_t)(r0 + q * 4 + r) * SEQ + tn];

    // E' rows for this step's epilogue (K-loop hides the gather latency)
    float ev[4][4];
#pragma unroll
    for (int j = 0; j < 4; ++j)
#pragma unroll
      for (int r = 0; r < 4; ++r)
        ev[j][r] = E[(size_t)tokc[r] * HID + wave * 64 + j * 16 + nn];

    i32x4 acc[4], accy;
#pragma unroll
    for (int j = 0; j < 4; ++j) acc[j] = i32x4{0, 0, 0, 0};
    accy = i32x4{0, 0, 0, 0};

    if (t > 0) {
#pragma unroll
      for (int kt = 0; kt < 8; ++kt) {
        const i32x4 a = *(const i32x4*)&hbuf[nn][kt * 64 + q * 16];
        acc[0] = __builtin_amdgcn_mfma_i32_16x16x64_i8(a, wa[0][kt], acc[0], 0, 0, 0);
        acc[1] = __builtin_amdgcn_mfma_i32_16x16x64_i8(a, wa[1][kt], acc[1], 0, 0, 0);
        acc[2] = __builtin_amdgcn_mfma_i32_16x16x64_i8(a, wv[0][kt], acc[2], 0, 0, 0);
        acc[3] = __builtin_amdgcn_mfma_i32_16x16x64_i8(a, wv[1][kt], acc[3], 0, 0, 0);
        accy   = __builtin_amdgcn_mfma_i32_16x16x64_i8(a, wy[kt],    accy,   0, 0, 0);
      }
    }
    // read->write barrier (A-reads consumed at MFMA issue; no waitcnt needed)
    asm volatile("s_barrier" ::: "memory");

    // epilogue: idx = clamp(acc*fq + E', 0, LUTN-1); h_i8 = lut[idx]
    // D layout: row m=q*4+r, col nn (verified)
#pragma unroll
    for (int j = 0; j < 4; ++j) {
      const int col = wave * 64 + j * 16 + nn;
#pragma unroll
      for (int r = 0; r < 4; ++r) {
        const int m = q * 4 + r;
        const float idxf = (float)acc[j][r] * fq + ev[j][r];
        const float idxc = __builtin_amdgcn_fmed3f(idxf, 0.f, (float)(LUTN - 1));
        const int idx = (int)idxc;          // trunc; +0.5 baked into E' => round-nearest
        hbuf[m][col] = lut[idx];
        if (t == SEQ - 1) {                 // exact fp32 h for the hT output only
          const float z = (idxf - 8192.5f) * (1.f / 2048.f);
          outH[(size_t)(r0 + m) * HID + col] = fast_tanh(z);
        }
      }
    }
    // write-publish barrier: drain LDS (LUT reads + h writes)
    asm volatile("s_waitcnt lgkmcnt(0)\n\ts_barrier" ::: "memory");

    // y_{t-1} epilogue — off the critical path, overlaps next step's loads
    if (t > 0) {
#pragma unroll
      for (int r = 0; r < 4; ++r) {
        const int m = q * 4 + r;
        out[((size_t)(r0 + m) * SEQ + (t - 1)) * VOCAB + wave * 16 + nn] =
            (float)accy[r] * fy + bo;
      }
    }

#pragma unroll
    for (int r = 0; r < 4; ++r) tokc[r] = tokn[r];
  }

  // final y pass: hbuf holds h_{SEQ-1} (published by the loop's last barrier)
  {
    i32x4 accy = i32x4{0, 0, 0, 0};
#pragma unroll
    for (int kt = 0; kt < 8; ++kt) {
      const i32x4 a = *(const i32x4*)&hbuf[nn][kt * 64 + q * 16];
      accy = __builtin_amdgcn_mfma_i32_16x16x64_i8(a, wy[kt], accy, 0, 0, 0);
    }
#pragma unroll
    for (int r = 0; r < 4; ++r) {
      const int m = q * 4 + r;
      out[((size_t)(r0 + m) * SEQ + (SEQ - 1)) * VOCAB + wave * 16 + nn] =
          (float)accy[r] * fy + bo;
    }
  }
}

extern "C" void kernel_launch(void* const* d_in, const int* in_sizes, int n_in,
                              void* d_out, int out_size, void* d_ws, size_t ws_size,
                              hipStream_t stream) {
  const int*   x    = (const int*)d_in[0];
  const float* emb  = (const float*)d_in[1];
  const float* W_ih = (const float*)d_in[2];
  const float* b_ih = (const float*)d_in[3];
  const float* W_hh = (const float*)d_in[4];
  const float* b_hh = (const float*)d_in[5];
  const float* W_ho = (const float*)d_in[6];
  const float* b_o  = (const float*)d_in[7];
  float* out = (float*)d_out;

  char* ws = (char*)d_ws;
  float*        E      = (float*)ws;                        // 256 KB (pre-baked E')
  uint4*        Wf8    = (uint4*)(ws + (256 << 10));        // 320 KB (40 nt x 8 x 1 KB)
  unsigned int* scu    = (unsigned int*)(ws + 589824);      // 2 scale slots
  const float*  scf    = (const float*)scu;

  hipMemsetAsync(scu, 0, 8, stream);   // ws is poisoned 0xAA every launch
  maxred_kernel<<<64, 256, 0, stream>>>(W_hh, HID * HID, scu + 0);
  maxred_kernel<<<16, 256, 0, stream>>>(W_ho, HID * VOCAB, scu + 1);
  eproj_kernel<<<VOCAB / 8, 512, 0, stream>>>(emb, W_ih, b_ih, b_hh, E);
  pack8_kernel<<<320, 64, 0, stream>>>(W_hh, W_ho, scf, Wf8);
  rnn_kernel<<<16, 512, 0, stream>>>(x, E, Wf8, scf, b_o, out,
                                     out + (size_t)BATCH * SEQ * VOCAB);
}